// Round 15
// baseline (160.090 us; speedup 1.0000x reference)
//
#include <hip/hip_runtime.h>

using short8 = __attribute__((ext_vector_type(8))) short;
using f32x4  = __attribute__((ext_vector_type(4))) float;

#define SCALE_Q 0.17677669529663687f   // 32^-0.5
#define NCHUNK 16

__device__ __forceinline__ unsigned short f2bf(float f) {
  unsigned u = __float_as_uint(f);
  return (unsigned short)((u + 0x7FFFu + ((u >> 16) & 1u)) >> 16);  // RNE
}
__device__ __forceinline__ float bf2f(unsigned h) { return __uint_as_float(h << 16); }

__device__ __forceinline__ void bf8_to_f(uint4 r, float* o) {
  o[0] = bf2f(r.x & 0xffffu); o[1] = bf2f(r.x >> 16);
  o[2] = bf2f(r.y & 0xffffu); o[3] = bf2f(r.y >> 16);
  o[4] = bf2f(r.z & 0xffffu); o[5] = bf2f(r.z >> 16);
  o[6] = bf2f(r.w & 0xffffu); o[7] = bf2f(r.w >> 16);
}

// ---------------- prep: x fp32 -> bf16; transpose-convert weights ----------------
__global__ __launch_bounds__(256) void prep_kernel(
    const float* __restrict__ x, const float* __restrict__ wqkv, const float* __restrict__ wout,
    unsigned short* __restrict__ xb, unsigned short* __restrict__ wqkvT,
    unsigned short* __restrict__ woutT) {
  const int blk = blockIdx.x;
  if (blk < 16384) {
    const size_t i = ((size_t)blk * 256 + threadIdx.x) * 4;
    const float4 v = *(const float4*)(x + i);
    *(ushort4*)(xb + i) = make_ushort4(f2bf(v.x), f2bf(v.y), f2bf(v.z), f2bf(v.w));
  } else if (blk < 16384 + 768) {
    const int n = blk - 16384, k = threadIdx.x;            // wqkvT[n][k] = wqkv[k][n]
    wqkvT[n * 256 + k] = f2bf(wqkv[(size_t)k * 768 + n]);
  } else {
    const int c = blk - 16384 - 768, f = threadIdx.x;      // woutT[c][f] = wout[f][c]
    woutT[c * 256 + f] = f2bf(wout[(size_t)f * 256 + c]);
  }
}

// ---------------- gemm_qkv: R14 dbuf skeleton + 2-deep prefetch ------------------
// qkv = xb[65536][256] * wqkvT[768][256]^T. 128x128 tile, BK=32, padded LDS x2,
// 4 waves (2x2), 4x4 frags of 16x16x32, rolled loop (runtime K -> VGPR 76).
// Pipeline per iter (2-deep, single reg set):
//   ds_read+MFMA(t from buf cur) -> ds_write(t+1 regs -> buf^1; vmcnt wait is on
//   loads issued a FULL iteration ago) -> issue loads(t+2 -> regs) -> barrier.
// MFMA operands SWAPPED (R8-verified): lane (fr,hi) reg r holds
// D[r0 + mi*16 + fr][cb + nj*16 + hi*4 + r] -> packed stores, 2-shfl q-softmax.
// Bijective XCD chunk remap: same-bm strips co-XCD (FETCH ~18 MB).
// bn 0..1 -> fused q-softmax into QS; bn 2..3 -> k, bn 4..5 -> v into KV[.][512].
__global__ __launch_bounds__(256) void gemm_qkv(
    const unsigned short* __restrict__ A, const unsigned short* __restrict__ BT,
    unsigned short* __restrict__ KV, unsigned short* __restrict__ QS, int K) {
  __shared__ unsigned short As[2][128][40];
  __shared__ unsigned short Bs[2][128][40];
  const int cpx = (int)gridDim.x >> 3;
  const int lin = ((int)blockIdx.x & 7) * cpx + ((int)blockIdx.x >> 3);
  const int bn = lin % 6, bm = lin / 6;
  const int tid = threadIdx.x, lane = tid & 63, wid = tid >> 6;
  const int wr = wid >> 1, wc = wid & 1;
  const int fr = lane & 15, hi = lane >> 4, fk = hi * 8;
  f32x4 acc[4][4] = {};
  const size_t abase = (size_t)bm * 128 * K;
  const size_t bbase = (size_t)bn * 128 * K;

  const int srow = tid >> 2, skc = (tid & 3) * 8;   // 2 chunks/thread per matrix
  uint4 ra0, ra1, rb0, rb1;
  const unsigned short* Ap = A + abase + (size_t)srow * K + skc;
  const unsigned short* Bp = BT + bbase + (size_t)srow * K + skc;

  // prologue: tile 0 -> buf0; issue tile 1 loads (fly across first compute)
  ra0 = *(const uint4*)(Ap);            ra1 = *(const uint4*)(Ap + (size_t)64 * K);
  rb0 = *(const uint4*)(Bp);            rb1 = *(const uint4*)(Bp + (size_t)64 * K);
  *(uint4*)&As[0][srow][skc] = ra0;     *(uint4*)&As[0][srow + 64][skc] = ra1;
  *(uint4*)&Bs[0][srow][skc] = rb0;     *(uint4*)&Bs[0][srow + 64][skc] = rb1;
  const int ktiles = K >> 5;
  if (ktiles > 1) {
    ra0 = *(const uint4*)(Ap + 32);     ra1 = *(const uint4*)(Ap + (size_t)64 * K + 32);
    rb0 = *(const uint4*)(Bp + 32);     rb1 = *(const uint4*)(Bp + (size_t)64 * K + 32);
  }
  __syncthreads();

  int cur = 0;
  for (int t = 0; t < ktiles; ++t) {
    short8 af[4], bfv[4];
#pragma unroll
    for (int i = 0; i < 4; ++i) {
      af[i]  = *(const short8*)&As[cur][wr * 64 + i * 16 + fr][fk];
      bfv[i] = *(const short8*)&Bs[cur][wc * 64 + i * 16 + fr][fk];
    }
#pragma unroll
    for (int mi = 0; mi < 4; ++mi)
#pragma unroll
      for (int nj = 0; nj < 4; ++nj)  // swapped operands
        acc[mi][nj] = __builtin_amdgcn_mfma_f32_16x16x32_bf16(bfv[nj], af[mi], acc[mi][nj], 0, 0, 0);
    if (t + 1 < ktiles) {
      // write tile t+1 (loads aged one full iteration) into the other buffer
      *(uint4*)&As[cur ^ 1][srow][skc] = ra0;  *(uint4*)&As[cur ^ 1][srow + 64][skc] = ra1;
      *(uint4*)&Bs[cur ^ 1][srow][skc] = rb0;  *(uint4*)&Bs[cur ^ 1][srow + 64][skc] = rb1;
      if (t + 2 < ktiles) {              // issue tile t+2 loads (regs free after write)
        const int kt = (t + 2) * 32;
        ra0 = *(const uint4*)(Ap + kt);  ra1 = *(const uint4*)(Ap + (size_t)64 * K + kt);
        rb0 = *(const uint4*)(Bp + kt);  rb1 = *(const uint4*)(Bp + (size_t)64 * K + kt);
      }
    }
    __syncthreads();                     // single barrier per iteration
    cur ^= 1;
  }

  const size_t r0 = (size_t)bm * 128 + wr * 64;
  if (bn < 2) {
    // q strips: per (row, head p) softmax over d=32. Lane holds 8 of the 32
    // d-values; reduce across hi groups with 2 shfl_xor (16, 32).
    const int c0 = bn * 128 + wc * 64;
#pragma unroll
    for (int mi = 0; mi < 4; ++mi) {
      const size_t row = r0 + mi * 16 + fr;
#pragma unroll
      for (int p = 0; p < 2; ++p) {
        const f32x4 a0 = acc[mi][2 * p], a1 = acc[mi][2 * p + 1];
        float mx = fmaxf(fmaxf(fmaxf(a0[0], a0[1]), fmaxf(a0[2], a0[3])),
                         fmaxf(fmaxf(a1[0], a1[1]), fmaxf(a1[2], a1[3])));
        mx = fmaxf(mx, __shfl_xor(mx, 16, 64));
        mx = fmaxf(mx, __shfl_xor(mx, 32, 64));
        float e0[4], e1[4], s = 0.f;
#pragma unroll
        for (int r = 0; r < 4; ++r) {
          e0[r] = __expf(a0[r] - mx); e1[r] = __expf(a1[r] - mx);
          s += e0[r] + e1[r];
        }
        s += __shfl_xor(s, 16, 64);
        s += __shfl_xor(s, 32, 64);
        const float inv = SCALE_Q / s;
        unsigned short* qp = QS + row * 256 + c0 + p * 32 + hi * 4;
        *(ushort4*)(qp)      = make_ushort4(f2bf(e0[0]*inv), f2bf(e0[1]*inv), f2bf(e0[2]*inv), f2bf(e0[3]*inv));
        *(ushort4*)(qp + 16) = make_ushort4(f2bf(e1[0]*inv), f2bf(e1[1]*inv), f2bf(e1[2]*inv), f2bf(e1[3]*inv));
      }
    }
    return;
  }
  const int colbase = (bn - 2) * 128 + wc * 64;   // kv row = 512 cols (k 0..255, v 256+)
#pragma unroll
  for (int mi = 0; mi < 4; ++mi) {
    const size_t row = r0 + mi * 16 + fr;
#pragma unroll
    for (int nj = 0; nj < 4; ++nj) {
      const int col0 = colbase + nj * 16 + hi * 4;
      const f32x4 v = acc[mi][nj];
      *(ushort4*)(KV + row * 512 + col0) =
          make_ushort4(f2bf(v[0]), f2bf(v[1]), f2bf(v[2]), f2bf(v[3]));
    }
  }
}

// ---------------- gemm_out: same 2-deep dbuf body, batched, fp32 out -------------
// 1D grid 1024, XCD-chunked with bn fastest: both bn strips of one (bm,z) run
// adjacently on the same XCD -> 2nd qs A-tile read is an L2 hit.
__global__ __launch_bounds__(256) void gemm_out(
    const unsigned short* __restrict__ A, const unsigned short* __restrict__ BT,
    float* __restrict__ D, int K) {
  __shared__ unsigned short As[2][128][40];
  __shared__ unsigned short Bs[2][128][40];
  const int cpx = (int)gridDim.x >> 3;
  const int lin = ((int)blockIdx.x & 7) * cpx + ((int)blockIdx.x >> 3);
  const int bn = lin & 1, bm = (lin >> 1) & 31, bz = lin >> 6;
  const int tid = threadIdx.x, lane = tid & 63, wid = tid >> 6;
  const int wr = wid >> 1, wc = wid & 1;
  const int fr = lane & 15, hi = lane >> 4, fk = hi * 8;
  f32x4 acc[4][4] = {};
  const size_t abase = (size_t)bz * 4096 * 256 + (size_t)bm * 128 * K;
  const size_t bbase = (size_t)bz * 256 * 256 + (size_t)bn * 128 * K;

  const int srow = tid >> 2, skc = (tid & 3) * 8;
  uint4 ra0, ra1, rb0, rb1;
  const unsigned short* Ap = A + abase + (size_t)srow * K + skc;
  const unsigned short* Bp = BT + bbase + (size_t)srow * K + skc;

  ra0 = *(const uint4*)(Ap);            ra1 = *(const uint4*)(Ap + (size_t)64 * K);
  rb0 = *(const uint4*)(Bp);            rb1 = *(const uint4*)(Bp + (size_t)64 * K);
  *(uint4*)&As[0][srow][skc] = ra0;     *(uint4*)&As[0][srow + 64][skc] = ra1;
  *(uint4*)&Bs[0][srow][skc] = rb0;     *(uint4*)&Bs[0][srow + 64][skc] = rb1;
  const int ktiles = K >> 5;
  if (ktiles > 1) {
    ra0 = *(const uint4*)(Ap + 32);     ra1 = *(const uint4*)(Ap + (size_t)64 * K + 32);
    rb0 = *(const uint4*)(Bp + 32);     rb1 = *(const uint4*)(Bp + (size_t)64 * K + 32);
  }
  __syncthreads();

  int cur = 0;
  for (int t = 0; t < ktiles; ++t) {
    short8 af[4], bfv[4];
#pragma unroll
    for (int i = 0; i < 4; ++i) {
      af[i]  = *(const short8*)&As[cur][wr * 64 + i * 16 + fr][fk];
      bfv[i] = *(const short8*)&Bs[cur][wc * 64 + i * 16 + fr][fk];
    }
#pragma unroll
    for (int mi = 0; mi < 4; ++mi)
#pragma unroll
      for (int nj = 0; nj < 4; ++nj)
        acc[mi][nj] = __builtin_amdgcn_mfma_f32_16x16x32_bf16(bfv[nj], af[mi], acc[mi][nj], 0, 0, 0);
    if (t + 1 < ktiles) {
      *(uint4*)&As[cur ^ 1][srow][skc] = ra0;  *(uint4*)&As[cur ^ 1][srow + 64][skc] = ra1;
      *(uint4*)&Bs[cur ^ 1][srow][skc] = rb0;  *(uint4*)&Bs[cur ^ 1][srow + 64][skc] = rb1;
      if (t + 2 < ktiles) {
        const int kt = (t + 2) * 32;
        ra0 = *(const uint4*)(Ap + kt);  ra1 = *(const uint4*)(Ap + (size_t)64 * K + kt);
        rb0 = *(const uint4*)(Bp + kt);  rb1 = *(const uint4*)(Bp + (size_t)64 * K + kt);
      }
    }
    __syncthreads();
    cur ^= 1;
  }

  const size_t r0 = (size_t)bm * 128 + wr * 64;
  const int colbase = bn * 128 + wc * 64;
  float* Dz = D + (size_t)bz * 4096 * 256;
#pragma unroll
  for (int mi = 0; mi < 4; ++mi) {
    const size_t row = r0 + mi * 16 + fr;
#pragma unroll
    for (int nj = 0; nj < 4; ++nj) {
      const f32x4 v = acc[mi][nj];
      *(float4*)(Dz + row * 256 + colbase + nj * 16 + hi * 4) =
          make_float4(v[0], v[1], v[2], v[3]);
    }
  }
}

// ---------------- ctx partials: per (b,h,chunk): sum_n exp(k[d,n])*v[e,n] ---------
// kv layout [65536][512]: k at cols 0..255, v at 256..511.
__global__ __launch_bounds__(256) void ctx_part_kernel(const unsigned short* __restrict__ kv,
                                                       float* __restrict__ part,
                                                       float* __restrict__ spart) {
  const int blk = blockIdx.x;
  const int bh = blk >> 4, chunk = blk & 15;
  const int b = bh >> 3, h = bh & 7;
  const int tid = threadIdx.x, d = tid & 31, g = tid >> 5;
  const unsigned short* kbase =
      kv + (size_t)b * 4096 * 512 + h * 32 + (size_t)chunk * 256 * 512;
  const unsigned short* vbase = kbase + 256;

  __shared__ float ek[64][36], vv[64][36];
  float a0 = 0.f, a1 = 0.f, a2 = 0.f, a3 = 0.f, ssum = 0.f;
  const int e0 = g * 4;
  const int sn = tid >> 2, sc = (tid & 3) * 8;
  const unsigned short* kp0 = kbase + (size_t)sn * 512 + sc;
  const unsigned short* vp0 = vbase + (size_t)sn * 512 + sc;
  uint4 kr = *(const uint4*)kp0;
  uint4 vr = *(const uint4*)vp0;
  for (int n0 = 0; n0 < 256; n0 += 64) {
    float kf[8], vf[8];
    bf8_to_f(kr, kf); bf8_to_f(vr, vf);
    uint4 krn = kr, vrn = vr;
    if (n0 + 64 < 256) {
      krn = *(const uint4*)(kp0 + (size_t)(n0 + 64) * 512);
      vrn = *(const uint4*)(vp0 + (size_t)(n0 + 64) * 512);
    }
#pragma unroll
    for (int j = 0; j < 8; ++j) { ek[sn][sc + j] = __expf(kf[j]); vv[sn][sc + j] = vf[j]; }
    __syncthreads();
#pragma unroll 8
    for (int i = 0; i < 64; ++i) {
      const float kd = ek[i][d];
      const float4 v4 = *(const float4*)&vv[i][e0];
      ssum += kd;
      a0 += kd * v4.x; a1 += kd * v4.y; a2 += kd * v4.z; a3 += kd * v4.w;
    }
    __syncthreads();
    kr = krn; vr = vrn;
  }
  float* pp = part + ((size_t)chunk * 128 + bh) * 1024 + d * 32 + e0;
  pp[0] = a0; pp[1] = a1; pp[2] = a2; pp[3] = a3;
  if (g == 0) spart[((size_t)chunk * 128 + bh) * 32 + d] = ssum;
}

// ---------------- ctx combine: ctx[d][e] = sum_c part / sum_c spart ---------------
__global__ __launch_bounds__(256) void ctx_combine_kernel(const float* __restrict__ part,
                                                          const float* __restrict__ spart,
                                                          float* __restrict__ ctx) {
  const int bh = blockIdx.x, tid = threadIdx.x;
  __shared__ float sinv[32];
  if (tid < 32) {
    float s = 0.f;
#pragma unroll
    for (int c = 0; c < NCHUNK; ++c) s += spart[((size_t)c * 128 + bh) * 32 + tid];
    sinv[tid] = 1.0f / s;
  }
  __syncthreads();
  float4 acc = make_float4(0.f, 0.f, 0.f, 0.f);
#pragma unroll
  for (int c = 0; c < NCHUNK; ++c) {
    const float4 p = *(const float4*)(part + ((size_t)c * 128 + bh) * 1024 + tid * 4);
    acc.x += p.x; acc.y += p.y; acc.z += p.z; acc.w += p.w;
  }
  const float si = sinv[tid >> 3];  // d = (tid*4)>>5
  float4* cp = (float4*)(ctx + (size_t)bh * 1024 + tid * 4);
  *cp = make_float4(acc.x * si, acc.y * si, acc.z * si, acc.w * si);
}

// ---------------- w2: W2T[b][c][(h,d)] = sum_e ctx[b,h,d,e] * woutT[c][(h,e)] -----
__global__ __launch_bounds__(256) void w2_kernel(const float* __restrict__ ctx,
                                                 const unsigned short* __restrict__ woutT,
                                                 unsigned short* __restrict__ W2T) {
  const int b = blockIdx.x >> 4, cg = blockIdx.x & 15;
  const int tid = threadIdx.x;
  __shared__ float cs[8 * 32 * 32];  // ctx[b]: 8 heads x 32d x 32e = 32 KB
  {
    const float4* src = (const float4*)(ctx + (size_t)b * 8192);
    float4* dst = (float4*)cs;
#pragma unroll
    for (int i = 0; i < 8; ++i) dst[tid + i * 256] = src[tid + i * 256];
  }
  __syncthreads();
  const int c = cg * 16 + (tid >> 4), chunk = tid & 15;
  const int h = chunk >> 1, d0 = (chunk & 1) * 16;
  float wf[32];
  {
    const uint4* wp = (const uint4*)(woutT + (size_t)c * 256 + h * 32);
    bf8_to_f(wp[0], wf + 0); bf8_to_f(wp[1], wf + 8);
    bf8_to_f(wp[2], wf + 16); bf8_to_f(wp[3], wf + 24);
  }
  unsigned short o[16];
#pragma unroll
  for (int dd = 0; dd < 16; ++dd) {
    const float* cp = cs + h * 1024 + (d0 + dd) * 32;
    float acc = 0.f;
#pragma unroll
    for (int e = 0; e < 32; ++e) acc += cp[e] * wf[e];
    o[dd] = f2bf(acc);
  }
  uint4* op = (uint4*)(W2T + ((size_t)b * 256 + c) * 256 + chunk * 16);
  op[0] = make_uint4((unsigned)o[0] | ((unsigned)o[1] << 16), (unsigned)o[2] | ((unsigned)o[3] << 16),
                     (unsigned)o[4] | ((unsigned)o[5] << 16), (unsigned)o[6] | ((unsigned)o[7] << 16));
  op[1] = make_uint4((unsigned)o[8] | ((unsigned)o[9] << 16), (unsigned)o[10] | ((unsigned)o[11] << 16),
                     (unsigned)o[12] | ((unsigned)o[13] << 16), (unsigned)o[14] | ((unsigned)o[15] << 16));
}

extern "C" void kernel_launch(void* const* d_in, const int* in_sizes, int n_in,
                              void* d_out, int out_size, void* d_ws, size_t ws_size,
                              hipStream_t stream) {
  const float* x     = (const float*)d_in[0];  // [16,64,64,256] = [65536][256]
  const float* wqkv  = (const float*)d_in[1];  // [256,768]
  const float* wout  = (const float*)d_in[2];  // [256,256]
  float* out = (float*)d_out;                  // [65536,256] fp32

  char* ws = (char*)d_ws;
  unsigned short* xb    = (unsigned short*)(ws);                 // 32 MB (dead after gemm_qkv)
  unsigned short* wqkvT = (unsigned short*)(ws + 33554432);      // 384 KB
  unsigned short* woutT = (unsigned short*)(ws + 33947648);      // 128 KB
  unsigned short* kv    = (unsigned short*)(ws + 34078720);      // 64 MB [65536][512]
  float*          ctx   = (float*)        (ws + 101187584);      // 512 KB [128][32][32]
  unsigned short* qs    = (unsigned short*)(ws + 101711872);     // 32 MB [65536][256]
  // reuse xb region (dead after gemm_qkv):
  float*          part  = (float*)(ws);                          // 8 MB [16][128][1024]
  float*          spart = (float*)(ws + 8388608);                // 256 KB [16][128][32]
  unsigned short* W2T   = (unsigned short*)(ws + 12582912);      // 2 MB [16][256][256]

  prep_kernel<<<16384 + 768 + 256, 256, 0, stream>>>(x, wqkv, wout, xb, wqkvT, woutT);
  // gemm1: 6 bn strips (q 0..1 -> softmax -> qs; k 2..3 / v 4..5 -> kv[.][512]).
  // 1D grid 3072, XCD-swizzled.
  gemm_qkv<<<3072, 256, 0, stream>>>(xb, wqkvT, kv, qs, 256);
  ctx_part_kernel<<<2048, 256, 0, stream>>>(kv, part, spart);
  ctx_combine_kernel<<<128, 256, 0, stream>>>(part, spart, ctx);
  w2_kernel<<<256, 256, 0, stream>>>(ctx, woutT, W2T);
  // gemm2: batched z=16, M=4096, N=256, K=256; 1D grid 1024, XCD-chunked (bn fast).
  gemm_out<<<1024, 256, 0, stream>>>(qs, W2T, out, 256);
}

// Round 16
// 152.649 us; speedup vs baseline: 1.0487x; 1.0487x over previous
//
#include <hip/hip_runtime.h>
#include <hip/hip_bf16.h>

using short8 = __attribute__((ext_vector_type(8))) short;
using f32x4  = __attribute__((ext_vector_type(4))) float;

#define SCALE_Q 0.17677669529663687f   // 32^-0.5
#define NCHUNK 16

__device__ __forceinline__ unsigned short f2bf(float f) {
  unsigned u = __float_as_uint(f);
  return (unsigned short)((u + 0x7FFFu + ((u >> 16) & 1u)) >> 16);  // RNE (scalar path)
}
__device__ __forceinline__ float bf2f(unsigned h) { return __uint_as_float(h << 16); }

// packed 2x f32 -> 2x bf16 (RNE). Written as plain casts so the compiler can
// emit v_cvt_pk_bf16_f32 (m240: hand-written rounding blocks this).
__device__ __forceinline__ unsigned pk2(float a, float b) {
  union { __hip_bfloat162 h; unsigned u; } cv;
  cv.h = __float22bfloat162_rn(make_float2(a, b));
  return cv.u;
}

__device__ __forceinline__ void bf8_to_f(uint4 r, float* o) {
  o[0] = bf2f(r.x & 0xffffu); o[1] = bf2f(r.x >> 16);
  o[2] = bf2f(r.y & 0xffffu); o[3] = bf2f(r.y >> 16);
  o[4] = bf2f(r.z & 0xffffu); o[5] = bf2f(r.z >> 16);
  o[6] = bf2f(r.w & 0xffffu); o[7] = bf2f(r.w >> 16);
}

// ---------------- prep: transpose-convert WEIGHTS only (x cvt fused in gemm_qkv) --
__global__ __launch_bounds__(256) void prep_kernel(
    const float* __restrict__ wqkv, const float* __restrict__ wout,
    unsigned short* __restrict__ wqkvT, unsigned short* __restrict__ woutT) {
  const int blk = blockIdx.x;
  if (blk < 768) {
    const int n = blk, k = threadIdx.x;                    // wqkvT[n][k] = wqkv[k][n]
    wqkvT[n * 256 + k] = f2bf(wqkv[(size_t)k * 768 + n]);
  } else {
    const int c = blk - 768, f = threadIdx.x;              // woutT[c][f] = wout[f][c]
    woutT[c * 256 + f] = f2bf(wout[(size_t)f * 256 + c]);
  }
}

// ---------------- gemm_qkv: R14 dbuf 1-deep pipeline + in-flight x conversion ----
// qkv = x[65536][256](fp32) * wqkvT[768][256]^T(bf16). 128x128 tile, BK=32,
// padded LDS x2, 4 waves (2x2), 4x4 frags of 16x16x32, rolled loop (VGPR low).
// Pipeline per iter (R14-verified, 65 us):
//   issue loads(t+1) -> ds_read+MFMA(t) -> cvt_pk+ds_write(t+1 -> buf^1) -> barrier.
// A is fp32, converted bf16 at ds_write via pk2 (compiler v_cvt_pk_bf16_f32);
// prep's 96 MB x-pass is deleted. Bijective XCD chunk remap keeps the fp32 A
// tile (128 KB) L2-hot across the 6 strips of one bm (R11: FETCH ~34 MB).
// MFMA operands SWAPPED (R8-verified): lane (fr,hi) reg r holds
// D[r0 + mi*16 + fr][cb + nj*16 + hi*4 + r] -> packed stores, 2-shfl q-softmax.
// bn 0..1 -> fused q-softmax into QS; bn 2..3 -> k, bn 4..5 -> v into KV[.][512].
__global__ __launch_bounds__(256) void gemm_qkv(
    const float* __restrict__ X, const unsigned short* __restrict__ BT,
    unsigned short* __restrict__ KV, unsigned short* __restrict__ QS, int K) {
  __shared__ unsigned short As[2][128][40];
  __shared__ unsigned short Bs[2][128][40];
  const int cpx = (int)gridDim.x >> 3;
  const int lin = ((int)blockIdx.x & 7) * cpx + ((int)blockIdx.x >> 3);
  const int bn = lin % 6, bm = lin / 6;
  const int tid = threadIdx.x, lane = tid & 63, wid = tid >> 6;
  const int wr = wid >> 1, wc = wid & 1;
  const int fr = lane & 15, hi = lane >> 4, fk = hi * 8;
  f32x4 acc[4][4] = {};

  const int srow = tid >> 2, skc = (tid & 3) * 8;   // 8 elems/chunk, 2 chunks per matrix
  const float* Ap = X + (size_t)bm * 128 * K + (size_t)srow * K + skc;
  const unsigned short* Bp = BT + (size_t)bn * 128 * K + (size_t)srow * K + skc;

  float4 fa0, fa1, fa2, fa3; uint4 rb0, rb1;
  // prologue: tile 0
  fa0 = *(const float4*)(Ap);                       fa1 = *(const float4*)(Ap + 4);
  fa2 = *(const float4*)(Ap + (size_t)64 * K);      fa3 = *(const float4*)(Ap + (size_t)64 * K + 4);
  rb0 = *(const uint4*)(Bp);                        rb1 = *(const uint4*)(Bp + (size_t)64 * K);
  *(uint4*)&As[0][srow][skc] =
      make_uint4(pk2(fa0.x, fa0.y), pk2(fa0.z, fa0.w), pk2(fa1.x, fa1.y), pk2(fa1.z, fa1.w));
  *(uint4*)&As[0][srow + 64][skc] =
      make_uint4(pk2(fa2.x, fa2.y), pk2(fa2.z, fa2.w), pk2(fa3.x, fa3.y), pk2(fa3.z, fa3.w));
  *(uint4*)&Bs[0][srow][skc] = rb0;                 *(uint4*)&Bs[0][srow + 64][skc] = rb1;
  __syncthreads();

  const int ktiles = K >> 5;
  int cur = 0;
  for (int t = 0; t < ktiles; ++t) {
    if (t + 1 < ktiles) {                 // issue next tile's loads (fly under MFMA)
      const int kt = (t + 1) * 32;
      fa0 = *(const float4*)(Ap + kt);                   fa1 = *(const float4*)(Ap + kt + 4);
      fa2 = *(const float4*)(Ap + (size_t)64 * K + kt);  fa3 = *(const float4*)(Ap + (size_t)64 * K + kt + 4);
      rb0 = *(const uint4*)(Bp + kt);                    rb1 = *(const uint4*)(Bp + (size_t)64 * K + kt);
    }
    short8 af[4], bfv[4];
#pragma unroll
    for (int i = 0; i < 4; ++i) {
      af[i]  = *(const short8*)&As[cur][wr * 64 + i * 16 + fr][fk];
      bfv[i] = *(const short8*)&Bs[cur][wc * 64 + i * 16 + fr][fk];
    }
#pragma unroll
    for (int mi = 0; mi < 4; ++mi)
#pragma unroll
      for (int nj = 0; nj < 4; ++nj)  // swapped operands
        acc[mi][nj] = __builtin_amdgcn_mfma_f32_16x16x32_bf16(bfv[nj], af[mi], acc[mi][nj], 0, 0, 0);
    if (t + 1 < ktiles) {                 // cvt + write-late into the other buffer
      *(uint4*)&As[cur ^ 1][srow][skc] =
          make_uint4(pk2(fa0.x, fa0.y), pk2(fa0.z, fa0.w), pk2(fa1.x, fa1.y), pk2(fa1.z, fa1.w));
      *(uint4*)&As[cur ^ 1][srow + 64][skc] =
          make_uint4(pk2(fa2.x, fa2.y), pk2(fa2.z, fa2.w), pk2(fa3.x, fa3.y), pk2(fa3.z, fa3.w));
      *(uint4*)&Bs[cur ^ 1][srow][skc] = rb0;  *(uint4*)&Bs[cur ^ 1][srow + 64][skc] = rb1;
    }
    __syncthreads();                      // single barrier per iteration
    cur ^= 1;
  }

  const size_t r0 = (size_t)bm * 128 + wr * 64;
  if (bn < 2) {
    // q strips: per (row, head p) softmax over d=32. Lane holds 8 of the 32
    // d-values; reduce across hi groups with 2 shfl_xor (16, 32).
    const int c0 = bn * 128 + wc * 64;
#pragma unroll
    for (int mi = 0; mi < 4; ++mi) {
      const size_t row = r0 + mi * 16 + fr;
#pragma unroll
      for (int p = 0; p < 2; ++p) {
        const f32x4 a0 = acc[mi][2 * p], a1 = acc[mi][2 * p + 1];
        float mx = fmaxf(fmaxf(fmaxf(a0[0], a0[1]), fmaxf(a0[2], a0[3])),
                         fmaxf(fmaxf(a1[0], a1[1]), fmaxf(a1[2], a1[3])));
        mx = fmaxf(mx, __shfl_xor(mx, 16, 64));
        mx = fmaxf(mx, __shfl_xor(mx, 32, 64));
        float e0[4], e1[4], s = 0.f;
#pragma unroll
        for (int r = 0; r < 4; ++r) {
          e0[r] = __expf(a0[r] - mx); e1[r] = __expf(a1[r] - mx);
          s += e0[r] + e1[r];
        }
        s += __shfl_xor(s, 16, 64);
        s += __shfl_xor(s, 32, 64);
        const float inv = SCALE_Q / s;
        unsigned short* qp = QS + row * 256 + c0 + p * 32 + hi * 4;
        *(uint2*)(qp)      = make_uint2(pk2(e0[0]*inv, e0[1]*inv), pk2(e0[2]*inv, e0[3]*inv));
        *(uint2*)(qp + 16) = make_uint2(pk2(e1[0]*inv, e1[1]*inv), pk2(e1[2]*inv, e1[3]*inv));
      }
    }
    return;
  }
  const int colbase = (bn - 2) * 128 + wc * 64;   // kv row = 512 cols (k 0..255, v 256+)
#pragma unroll
  for (int mi = 0; mi < 4; ++mi) {
    const size_t row = r0 + mi * 16 + fr;
#pragma unroll
    for (int nj = 0; nj < 4; ++nj) {
      const int col0 = colbase + nj * 16 + hi * 4;
      const f32x4 v = acc[mi][nj];
      *(uint2*)(KV + row * 512 + col0) = make_uint2(pk2(v[0], v[1]), pk2(v[2], v[3]));
    }
  }
}

// ---------------- gemm_out: R14 dbuf 1-deep body, batched, fp32 out --------------
// 1D grid 1024, XCD-chunked with bn fastest: both bn strips of one (bm,z) run
// adjacently on the same XCD -> 2nd qs A-tile read is an L2 hit.
__global__ __launch_bounds__(256) void gemm_out(
    const unsigned short* __restrict__ A, const unsigned short* __restrict__ BT,
    float* __restrict__ D, int K) {
  __shared__ unsigned short As[2][128][40];
  __shared__ unsigned short Bs[2][128][40];
  const int cpx = (int)gridDim.x >> 3;
  const int lin = ((int)blockIdx.x & 7) * cpx + ((int)blockIdx.x >> 3);
  const int bn = lin & 1, bm = (lin >> 1) & 31, bz = lin >> 6;
  const int tid = threadIdx.x, lane = tid & 63, wid = tid >> 6;
  const int wr = wid >> 1, wc = wid & 1;
  const int fr = lane & 15, hi = lane >> 4, fk = hi * 8;
  f32x4 acc[4][4] = {};
  const size_t abase = (size_t)bz * 4096 * 256 + (size_t)bm * 128 * K;
  const size_t bbase = (size_t)bz * 256 * 256 + (size_t)bn * 128 * K;

  const int srow = tid >> 2, skc = (tid & 3) * 8;
  uint4 ra0, ra1, rb0, rb1;
  const unsigned short* Ap = A + abase + (size_t)srow * K + skc;
  const unsigned short* Bp = BT + bbase + (size_t)srow * K + skc;

  ra0 = *(const uint4*)(Ap);            ra1 = *(const uint4*)(Ap + (size_t)64 * K);
  rb0 = *(const uint4*)(Bp);            rb1 = *(const uint4*)(Bp + (size_t)64 * K);
  *(uint4*)&As[0][srow][skc] = ra0;     *(uint4*)&As[0][srow + 64][skc] = ra1;
  *(uint4*)&Bs[0][srow][skc] = rb0;     *(uint4*)&Bs[0][srow + 64][skc] = rb1;
  __syncthreads();

  const int ktiles = K >> 5;
  int cur = 0;
  for (int t = 0; t < ktiles; ++t) {
    if (t + 1 < ktiles) {
      const int kt = (t + 1) * 32;
      ra0 = *(const uint4*)(Ap + kt);     ra1 = *(const uint4*)(Ap + (size_t)64 * K + kt);
      rb0 = *(const uint4*)(Bp + kt);     rb1 = *(const uint4*)(Bp + (size_t)64 * K + kt);
    }
    short8 af[4], bfv[4];
#pragma unroll
    for (int i = 0; i < 4; ++i) {
      af[i]  = *(const short8*)&As[cur][wr * 64 + i * 16 + fr][fk];
      bfv[i] = *(const short8*)&Bs[cur][wc * 64 + i * 16 + fr][fk];
    }
#pragma unroll
    for (int mi = 0; mi < 4; ++mi)
#pragma unroll
      for (int nj = 0; nj < 4; ++nj)
        acc[mi][nj] = __builtin_amdgcn_mfma_f32_16x16x32_bf16(bfv[nj], af[mi], acc[mi][nj], 0, 0, 0);
    if (t + 1 < ktiles) {
      *(uint4*)&As[cur ^ 1][srow][skc] = ra0;  *(uint4*)&As[cur ^ 1][srow + 64][skc] = ra1;
      *(uint4*)&Bs[cur ^ 1][srow][skc] = rb0;  *(uint4*)&Bs[cur ^ 1][srow + 64][skc] = rb1;
    }
    __syncthreads();
    cur ^= 1;
  }

  const size_t r0 = (size_t)bm * 128 + wr * 64;
  const int colbase = bn * 128 + wc * 64;
  float* Dz = D + (size_t)bz * 4096 * 256;
#pragma unroll
  for (int mi = 0; mi < 4; ++mi) {
    const size_t row = r0 + mi * 16 + fr;
#pragma unroll
    for (int nj = 0; nj < 4; ++nj) {
      const f32x4 v = acc[mi][nj];
      *(float4*)(Dz + row * 256 + colbase + nj * 16 + hi * 4) =
          make_float4(v[0], v[1], v[2], v[3]);
    }
  }
}

// ---------------- ctx partials: per (b,h,chunk): sum_n exp(k[d,n])*v[e,n] ---------
// kv layout [65536][512]: k at cols 0..255, v at 256..511.
__global__ __launch_bounds__(256) void ctx_part_kernel(const unsigned short* __restrict__ kv,
                                                       float* __restrict__ part,
                                                       float* __restrict__ spart) {
  const int blk = blockIdx.x;
  const int bh = blk >> 4, chunk = blk & 15;
  const int b = bh >> 3, h = bh & 7;
  const int tid = threadIdx.x, d = tid & 31, g = tid >> 5;
  const unsigned short* kbase =
      kv + (size_t)b * 4096 * 512 + h * 32 + (size_t)chunk * 256 * 512;
  const unsigned short* vbase = kbase + 256;

  __shared__ float ek[64][36], vv[64][36];
  float a0 = 0.f, a1 = 0.f, a2 = 0.f, a3 = 0.f, ssum = 0.f;
  const int e0 = g * 4;
  const int sn = tid >> 2, sc = (tid & 3) * 8;
  const unsigned short* kp0 = kbase + (size_t)sn * 512 + sc;
  const unsigned short* vp0 = vbase + (size_t)sn * 512 + sc;
  uint4 kr = *(const uint4*)kp0;
  uint4 vr = *(const uint4*)vp0;
  for (int n0 = 0; n0 < 256; n0 += 64) {
    float kf[8], vf[8];
    bf8_to_f(kr, kf); bf8_to_f(vr, vf);
    uint4 krn = kr, vrn = vr;
    if (n0 + 64 < 256) {
      krn = *(const uint4*)(kp0 + (size_t)(n0 + 64) * 512);
      vrn = *(const uint4*)(vp0 + (size_t)(n0 + 64) * 512);
    }
#pragma unroll
    for (int j = 0; j < 8; ++j) { ek[sn][sc + j] = __expf(kf[j]); vv[sn][sc + j] = vf[j]; }
    __syncthreads();
#pragma unroll 8
    for (int i = 0; i < 64; ++i) {
      const float kd = ek[i][d];
      const float4 v4 = *(const float4*)&vv[i][e0];
      ssum += kd;
      a0 += kd * v4.x; a1 += kd * v4.y; a2 += kd * v4.z; a3 += kd * v4.w;
    }
    __syncthreads();
    kr = krn; vr = vrn;
  }
  float* pp = part + ((size_t)chunk * 128 + bh) * 1024 + d * 32 + e0;
  pp[0] = a0; pp[1] = a1; pp[2] = a2; pp[3] = a3;
  if (g == 0) spart[((size_t)chunk * 128 + bh) * 32 + d] = ssum;
}

// ---------------- ctx combine: ctx[d][e] = sum_c part / sum_c spart ---------------
__global__ __launch_bounds__(256) void ctx_combine_kernel(const float* __restrict__ part,
                                                          const float* __restrict__ spart,
                                                          float* __restrict__ ctx) {
  const int bh = blockIdx.x, tid = threadIdx.x;
  __shared__ float sinv[32];
  if (tid < 32) {
    float s = 0.f;
#pragma unroll
    for (int c = 0; c < NCHUNK; ++c) s += spart[((size_t)c * 128 + bh) * 32 + tid];
    sinv[tid] = 1.0f / s;
  }
  __syncthreads();
  float4 acc = make_float4(0.f, 0.f, 0.f, 0.f);
#pragma unroll
  for (int c = 0; c < NCHUNK; ++c) {
    const float4 p = *(const float4*)(part + ((size_t)c * 128 + bh) * 1024 + tid * 4);
    acc.x += p.x; acc.y += p.y; acc.z += p.z; acc.w += p.w;
  }
  const float si = sinv[tid >> 3];  // d = (tid*4)>>5
  float4* cp = (float4*)(ctx + (size_t)bh * 1024 + tid * 4);
  *cp = make_float4(acc.x * si, acc.y * si, acc.z * si, acc.w * si);
}

// ---------------- w2: W2T[b][c][(h,d)] = sum_e ctx[b,h,d,e] * woutT[c][(h,e)] -----
__global__ __launch_bounds__(256) void w2_kernel(const float* __restrict__ ctx,
                                                 const unsigned short* __restrict__ woutT,
                                                 unsigned short* __restrict__ W2T) {
  const int b = blockIdx.x >> 4, cg = blockIdx.x & 15;
  const int tid = threadIdx.x;
  __shared__ float cs[8 * 32 * 32];  // ctx[b]: 8 heads x 32d x 32e = 32 KB
  {
    const float4* src = (const float4*)(ctx + (size_t)b * 8192);
    float4* dst = (float4*)cs;
#pragma unroll
    for (int i = 0; i < 8; ++i) dst[tid + i * 256] = src[tid + i * 256];
  }
  __syncthreads();
  const int c = cg * 16 + (tid >> 4), chunk = tid & 15;
  const int h = chunk >> 1, d0 = (chunk & 1) * 16;
  float wf[32];
  {
    const uint4* wp = (const uint4*)(woutT + (size_t)c * 256 + h * 32);
    bf8_to_f(wp[0], wf + 0); bf8_to_f(wp[1], wf + 8);
    bf8_to_f(wp[2], wf + 16); bf8_to_f(wp[3], wf + 24);
  }
  unsigned short o[16];
#pragma unroll
  for (int dd = 0; dd < 16; ++dd) {
    const float* cp = cs + h * 1024 + (d0 + dd) * 32;
    float acc = 0.f;
#pragma unroll
    for (int e = 0; e < 32; ++e) acc += cp[e] * wf[e];
    o[dd] = f2bf(acc);
  }
  uint4* op = (uint4*)(W2T + ((size_t)b * 256 + c) * 256 + chunk * 16);
  op[0] = make_uint4((unsigned)o[0] | ((unsigned)o[1] << 16), (unsigned)o[2] | ((unsigned)o[3] << 16),
                     (unsigned)o[4] | ((unsigned)o[5] << 16), (unsigned)o[6] | ((unsigned)o[7] << 16));
  op[1] = make_uint4((unsigned)o[8] | ((unsigned)o[9] << 16), (unsigned)o[10] | ((unsigned)o[11] << 16),
                     (unsigned)o[12] | ((unsigned)o[13] << 16), (unsigned)o[14] | ((unsigned)o[15] << 16));
}

extern "C" void kernel_launch(void* const* d_in, const int* in_sizes, int n_in,
                              void* d_out, int out_size, void* d_ws, size_t ws_size,
                              hipStream_t stream) {
  const float* x     = (const float*)d_in[0];  // [16,64,64,256] = [65536][256]
  const float* wqkv  = (const float*)d_in[1];  // [256,768]
  const float* wout  = (const float*)d_in[2];  // [256,256]
  float* out = (float*)d_out;                  // [65536,256] fp32

  char* ws = (char*)d_ws;
  float*          part  = (float*)(ws);                          // 8 MB [16][128][1024]
  float*          spart = (float*)(ws + 8388608);                // 256 KB [16][128][32]
  unsigned short* W2T   = (unsigned short*)(ws + 12582912);      // 2 MB [16][256][256]
  unsigned short* wqkvT = (unsigned short*)(ws + 33554432);      // 384 KB
  unsigned short* woutT = (unsigned short*)(ws + 33947648);      // 128 KB
  unsigned short* kv    = (unsigned short*)(ws + 34078720);      // 64 MB [65536][512]
  float*          ctx   = (float*)        (ws + 101187584);      // 512 KB [128][32][32]
  unsigned short* qs    = (unsigned short*)(ws + 101711872);     // 32 MB [65536][256]

  prep_kernel<<<1024, 256, 0, stream>>>(wqkv, wout, wqkvT, woutT);
  // gemm1: A = x fp32 (cvt_pk fused into staging), 6 bn strips (q 0..1 -> softmax
  // -> qs; k 2..3 / v 4..5 -> kv[.][512]). 1D grid 3072, XCD-swizzled.
  gemm_qkv<<<3072, 256, 0, stream>>>(x, wqkvT, kv, qs, 256);
  ctx_part_kernel<<<2048, 256, 0, stream>>>(kv, part, spart);
  ctx_combine_kernel<<<128, 256, 0, stream>>>(part, spart, ctx);
  w2_kernel<<<256, 256, 0, stream>>>(ctx, woutT, W2T);
  // gemm2: batched z=16, M=4096, N=256, K=256; 1D grid 1024, XCD-chunked (bn fast).
  gemm_out<<<1024, 256, 0, stream>>>(qs, W2T, out, 256);
}